// Round 9
// baseline (377.802 us; speedup 1.0000x reference)
//
#include <hip/hip_runtime.h>
#include <math.h>

#define NA 100000
#define NB 100000
#define DIM 128
#define NEDGE 1600000
#define ALPHA 0.1f
#define BCAP 32        // P(Poisson(16) > 32) ~ 1.5e-4 -> ~25 overflow edges, handled exactly
#define OVF_CAP 65536

// ---- workspace layout (bytes, all 64-aligned) ----
// Path A (wide): int2 bucket, total 52,957,120 (proven OK in R8).
// Path B (fallback): int bucket, total 40,157,120 (proven OK in R5).
#define WS_NEBF   0          // 25,600,000  bf16 new_emb[NB*DIM]
#define WS_WBF    25600000   //     32,768  bf16 W[DIM*DIM]
#define WS_SA     25632768   //    400,000  float s_a[NA]
#define WS_SB     26032768   //    400,000  float s_b[NB]
#define WS_CNT    26432768   //    400,000  int cnt[NA] (cursor; counts ALL edges of row)
#define WS_FLAG   26832768   //         64  int flags[16]: [0]=int64-layout, [1]=overflow counter
#define WS_OVF    26832832   //    524,288  int2 ovf[OVF_CAP] = (src,dst)
#define WS_PAIRS  27357120   // bucket array
#define WS_TOTAL_A (27357120 + (size_t)NA * BCAP * 8)   // 52,957,120 (R8 proven)
#define WS_TOTAL_B (27357120 + (size_t)NA * BCAP * 4)   // 40,157,120 (R5 proven)

// fused pre-pass partitions (non-atomic only — R3/R7: never co-schedule the atomic scatter)
#define NEWEMB_BLOCKS 782    // ceil(ceil(NB/32)/4)
#define SA_BLOCKS     25000  // NA/4
// prep partitions: 1 (edge detect) + 64 (W->bf16) + 391 (zero cnt+flags[1..])
#define PREP_W_BLOCKS 64
#define PREP_Z_BLOCKS 391

using bf16x8 = __attribute__((ext_vector_type(8))) short;
using f32x16 = __attribute__((ext_vector_type(16))) float;

__device__ inline short f2bf(float f) {   // RNE float->bf16
    union { float f; unsigned u; } v; v.f = f;
    const unsigned r = (v.u + 0x7FFFu + ((v.u >> 16) & 1u)) >> 16;
    return (short)r;
}

// block 0: edge-layout detect; blocks 1..64: W -> bf16; blocks 65..455: zero cnt + flags[1]
__global__ void k_prep(const int* __restrict__ edges32, int* __restrict__ flags,
                       const float* __restrict__ W, short* __restrict__ wbf,
                       int* __restrict__ cnt) {
    if (blockIdx.x == 0) {
        __shared__ int any;
        if (threadIdx.x == 0) any = 0;
        __syncthreads();
        if (edges32[2 * threadIdx.x + 1] != 0) atomicOr(&any, 1);
        __syncthreads();
        if (threadIdx.x == 0) flags[0] = (any == 0) ? 1 : 0;
    } else if (blockIdx.x <= PREP_W_BLOCKS) {
        const int i = (blockIdx.x - 1) * 256 + threadIdx.x;
        if (i < DIM * DIM) wbf[i] = f2bf(W[i]);
    } else {
        const int i = (blockIdx.x - 1 - PREP_W_BLOCKS) * 256 + threadIdx.x;
        if (i < NA) cnt[i] = 0;
        if (i == 0) flags[1] = 0;   // overflow counter (flags[0] written by block 0 - distinct addr)
    }
}

// Fused non-atomic pre-pass:
//   blocks [0,782): new_emb(bf16) = fb @ W^T + b ; s_b = new_emb @ a_bot (proven R2 body)
//   blocks [782, 782+25000): s_a = fa @ a_top, one wave per row (proven R2 body)
__global__ __launch_bounds__(256) void k_newemb_sa(
    const float* __restrict__ fb, const short* __restrict__ wbf,
    const float* __restrict__ bias, const float* __restrict__ avec,
    short* __restrict__ nebf, float* __restrict__ s_b,
    const float* __restrict__ fa, float* __restrict__ s_a)
{
    const int lane = threadIdx.x & 63;
    if (blockIdx.x < NEWEMB_BLOCKS) {
        const int wv = threadIdx.x >> 6;
        const int tile = blockIdx.x * 4 + wv;
        const int row0 = tile * 32;
        if (row0 >= NB) return;
        const int l31 = lane & 31;
        const int h = lane >> 5;

        f32x16 acc[4];
        #pragma unroll
        for (int nt = 0; nt < 4; ++nt)
            #pragma unroll
            for (int r = 0; r < 16; ++r) acc[nt][r] = 0.f;

        const float* arow = fb + (size_t)(row0 + l31) * DIM;   // A: m = lane&31

        #pragma unroll 2
        for (int s = 0; s < 8; ++s) {
            const int k0 = s * 16 + h * 8;                     // A/B: k = 8*(lane>>5)+j
            const float4 a0 = *(const float4*)(arow + k0);
            const float4 a1 = *(const float4*)(arow + k0 + 4);
            bf16x8 af;
            af[0] = f2bf(a0.x); af[1] = f2bf(a0.y); af[2] = f2bf(a0.z); af[3] = f2bf(a0.w);
            af[4] = f2bf(a1.x); af[5] = f2bf(a1.y); af[6] = f2bf(a1.z); af[7] = f2bf(a1.w);
            #pragma unroll
            for (int nt = 0; nt < 4; ++nt) {
                const int n = nt * 32 + l31;                   // B[k][n] = W[n][k]
                const bf16x8 bf = *(const bf16x8*)(wbf + n * DIM + k0);
                acc[nt] = __builtin_amdgcn_mfma_f32_32x32x16_bf16(af, bf, acc[nt], 0, 0, 0);
            }
        }

        float ab[4], bs[4];
        #pragma unroll
        for (int nt = 0; nt < 4; ++nt) {
            ab[nt] = avec[DIM + nt * 32 + l31];   // a_bot
            bs[nt] = bias[nt * 32 + l31];
        }
        float sb[16];
        #pragma unroll
        for (int r = 0; r < 16; ++r) {
            const int row = row0 + (r & 3) + 8 * (r >> 2) + 4 * h;  // C/D row map
            float p = 0.f;
            #pragma unroll
            for (int nt = 0; nt < 4; ++nt) {
                const float v = acc[nt][r] + bs[nt];
                nebf[(size_t)row * DIM + nt * 32 + l31] = f2bf(v);
                p += v * ab[nt];
            }
            #pragma unroll
            for (int m = 16; m; m >>= 1) p += __shfl_xor(p, m, 64);  // reduce over lane&31
            sb[r] = p;
        }
        if (l31 == 0) {
            #pragma unroll
            for (int r = 0; r < 16; ++r)
                s_b[row0 + (r & 3) + 8 * (r >> 2) + 4 * h] = sb[r];
        }
    } else {
        const int row = (blockIdx.x - NEWEMB_BLOCKS) * 4 + (threadIdx.x >> 6);
        if (row >= NA) return;
        const float2 v = *(const float2*)(fa + (size_t)row * DIM + 2 * lane);
        const float2 a = *(const float2*)(avec + 2 * lane);
        float p = v.x * a.x + v.y * a.y;
        #pragma unroll
        for (int m = 32; m; m >>= 1) p += __shfl_xor(p, m, 64);
        if (lane == 0) s_a[row] = p;
    }
}

__device__ inline float edge_w(float sar, float sb) {
    const float sc = sar + sb;
    const float el = (sc > 0.f) ? sc : ALPHA * expm1f(sc);
    return expf(el);
}

// ---- PATH A: scatter with w computed here, 8B (dst,w) entries (R8: 92us @1.2TB/s) ----
__global__ __launch_bounds__(256) void k_scatter_w(
    const void* __restrict__ edges, const int* __restrict__ flags,
    const float* __restrict__ s_a, const float* __restrict__ s_b,
    int* __restrict__ cnt, int2* __restrict__ bucket,
    int2* __restrict__ ovf, int* __restrict__ ovfcnt)
{
    const int e = blockIdx.x * 256 + threadIdx.x;
    if (e >= NEDGE) return;
    int src, dst;
    if (flags[0]) {
        const int4 v = ((const int4*)edges)[e];
        src = v.x; dst = v.z;
    } else {
        const int2 v = ((const int2*)edges)[e];
        src = v.x; dst = v.y;
    }
    const float w = edge_w(s_a[src], s_b[dst]);
    const int pos = atomicAdd(&cnt[src], 1);
    if (pos < BCAP) {
        bucket[(src << 5) + pos] = make_int2(dst, __float_as_int(w));
    } else {
        const int o = atomicAdd(ovfcnt, 1);
        if (o < OVF_CAP) ovf[o] = make_int2(src, dst);
    }
}

// ---- PATH B: 4B dst-only entries (R5 proven fallback) ----
__global__ __launch_bounds__(256) void k_scatter(
    const void* __restrict__ edges, const int* __restrict__ flags,
    int* __restrict__ cnt, int* __restrict__ bucket,
    int2* __restrict__ ovf, int* __restrict__ ovfcnt)
{
    const int e = blockIdx.x * 256 + threadIdx.x;
    if (e >= NEDGE) return;
    int src, dst;
    if (flags[0]) {
        const int4 v = ((const int4*)edges)[e];
        src = v.x; dst = v.z;
    } else {
        const int2 v = ((const int2*)edges)[e];
        src = v.x; dst = v.y;
    }
    const int pos = atomicAdd(&cnt[src], 1);
    if (pos < BCAP) {
        bucket[(src << 5) + pos] = dst;
    } else {
        const int o = atomicAdd(ovfcnt, 1);
        if (o < OVF_CAP) ovf[o] = make_int2(src, dst);
    }
}

// one wave per src row, quarter-wave per edge: 16 lanes x uint4 = full 256B bf16 row,
// 4-deep MLP (16 gathers in flight per wave).
#define ACC8(u, wt)                                                             \
    a0 += (wt) * __uint_as_float((u).x << 16);                                  \
    a1 += (wt) * __uint_as_float((u).x & 0xFFFF0000u);                          \
    a2 += (wt) * __uint_as_float((u).y << 16);                                  \
    a3 += (wt) * __uint_as_float((u).y & 0xFFFF0000u);                          \
    a4 += (wt) * __uint_as_float((u).z << 16);                                  \
    a5 += (wt) * __uint_as_float((u).z & 0xFFFF0000u);                          \
    a6 += (wt) * __uint_as_float((u).w << 16);                                  \
    a7 += (wt) * __uint_as_float((u).w & 0xFFFF0000u);

#define ROWAGG_REDUCE_STORE                                                     \
    a0 += __shfl_xor(a0, 16, 64); a0 += __shfl_xor(a0, 32, 64);                 \
    a1 += __shfl_xor(a1, 16, 64); a1 += __shfl_xor(a1, 32, 64);                 \
    a2 += __shfl_xor(a2, 16, 64); a2 += __shfl_xor(a2, 32, 64);                 \
    a3 += __shfl_xor(a3, 16, 64); a3 += __shfl_xor(a3, 32, 64);                 \
    a4 += __shfl_xor(a4, 16, 64); a4 += __shfl_xor(a4, 32, 64);                 \
    a5 += __shfl_xor(a5, 16, 64); a5 += __shfl_xor(a5, 32, 64);                 \
    a6 += __shfl_xor(a6, 16, 64); a6 += __shfl_xor(a6, 32, 64);                 \
    a7 += __shfl_xor(a7, 16, 64); a7 += __shfl_xor(a7, 32, 64);                 \
    wsum += __shfl_xor(wsum, 16, 64); wsum += __shfl_xor(wsum, 32, 64);         \
    if (q == 0) {                                                               \
        const float inv = 1.f / ((wsum == 0.f) ? 1.f : wsum);                   \
        float* o = out + (size_t)row * DIM + 8 * l;                             \
        *(float4*)o       = make_float4(a0 * inv, a1 * inv, a2 * inv, a3 * inv);\
        *(float4*)(o + 4) = make_float4(a4 * inv, a5 * inv, a6 * inv, a7 * inv);\
    }

// PATH A rowagg: w read from bucket (no s_b gather / expf per edge)
__global__ __launch_bounds__(256) void k_rowagg_w(
    const int* __restrict__ cnt, const int2* __restrict__ bucket_all,
    const float* __restrict__ s_a, const float* __restrict__ s_b,
    const unsigned* __restrict__ nebf, const int2* __restrict__ ovf,
    const int* __restrict__ flags, float* __restrict__ out)
{
    const int row = blockIdx.x * 4 + (threadIdx.x >> 6);
    if (row >= NA) return;
    const int lane = threadIdx.x & 63;
    const int l = lane & 15;
    const int q = lane >> 4;
    const int c = cnt[row];
    const int cb = (c > BCAP) ? BCAP : c;
    const int2* bucket = bucket_all + (row << 5);

    float a0 = 0.f, a1 = 0.f, a2 = 0.f, a3 = 0.f;
    float a4 = 0.f, a5 = 0.f, a6 = 0.f, a7 = 0.f, wsum = 0.f;
    int i = q;
    for (; i + 12 < cb; i += 16) {
        const int2 p0 = bucket[i];
        const int2 p1 = bucket[i + 4];
        const int2 p2 = bucket[i + 8];
        const int2 p3 = bucket[i + 12];
        const uint4 u0 = *(const uint4*)(nebf + (size_t)p0.x * (DIM / 2) + 4 * l);
        const uint4 u1 = *(const uint4*)(nebf + (size_t)p1.x * (DIM / 2) + 4 * l);
        const uint4 u2 = *(const uint4*)(nebf + (size_t)p2.x * (DIM / 2) + 4 * l);
        const uint4 u3 = *(const uint4*)(nebf + (size_t)p3.x * (DIM / 2) + 4 * l);
        const float w0 = __int_as_float(p0.y);
        const float w1 = __int_as_float(p1.y);
        const float w2 = __int_as_float(p2.y);
        const float w3 = __int_as_float(p3.y);
        ACC8(u0, w0) ACC8(u1, w1) ACC8(u2, w2) ACC8(u3, w3)
        wsum += (w0 + w1) + (w2 + w3);
    }
    for (; i + 4 < cb; i += 8) {
        const int2 p0 = bucket[i];
        const int2 p1 = bucket[i + 4];
        const uint4 u0 = *(const uint4*)(nebf + (size_t)p0.x * (DIM / 2) + 4 * l);
        const uint4 u1 = *(const uint4*)(nebf + (size_t)p1.x * (DIM / 2) + 4 * l);
        const float w0 = __int_as_float(p0.y);
        const float w1 = __int_as_float(p1.y);
        ACC8(u0, w0) ACC8(u1, w1)
        wsum += w0 + w1;
    }
    for (; i < cb; i += 4) {
        const int2 p = bucket[i];
        const uint4 u = *(const uint4*)(nebf + (size_t)p.x * (DIM / 2) + 4 * l);
        const float wv = __int_as_float(p.y);
        ACC8(u, wv)
        wsum += wv;
    }
    // exact overflow fold-in (~25 entries; w recomputed, negligible)
    int novf = flags[1];
    novf = (novf > OVF_CAP) ? OVF_CAP : novf;
    const float sar = s_a[row];
    for (int j = q; j < novf; j += 4) {
        const int2 pe = ovf[j];
        if (pe.x == row) {
            const uint4 u = *(const uint4*)(nebf + (size_t)pe.y * (DIM / 2) + 4 * l);
            const float wv = edge_w(sar, s_b[pe.y]);
            ACC8(u, wv)
            wsum += wv;
        }
    }
    ROWAGG_REDUCE_STORE
}

// PATH B rowagg: w recomputed from s_a + s_b (R5/R7 proven)
__global__ __launch_bounds__(256) void k_rowagg(
    const int* __restrict__ cnt, const int* __restrict__ bucket_all,
    const float* __restrict__ s_a, const float* __restrict__ s_b,
    const unsigned* __restrict__ nebf, const int2* __restrict__ ovf,
    const int* __restrict__ flags, float* __restrict__ out)
{
    const int row = blockIdx.x * 4 + (threadIdx.x >> 6);
    if (row >= NA) return;
    const int lane = threadIdx.x & 63;
    const int l = lane & 15;
    const int q = lane >> 4;
    const int c = cnt[row];
    const int cb = (c > BCAP) ? BCAP : c;
    const int* bucket = bucket_all + (row << 5);
    const float sar = s_a[row];

    float a0 = 0.f, a1 = 0.f, a2 = 0.f, a3 = 0.f;
    float a4 = 0.f, a5 = 0.f, a6 = 0.f, a7 = 0.f, wsum = 0.f;
    int i = q;
    for (; i + 12 < cb; i += 16) {
        const int d0 = bucket[i];
        const int d1 = bucket[i + 4];
        const int d2 = bucket[i + 8];
        const int d3 = bucket[i + 12];
        const uint4 u0 = *(const uint4*)(nebf + (size_t)d0 * (DIM / 2) + 4 * l);
        const uint4 u1 = *(const uint4*)(nebf + (size_t)d1 * (DIM / 2) + 4 * l);
        const uint4 u2 = *(const uint4*)(nebf + (size_t)d2 * (DIM / 2) + 4 * l);
        const uint4 u3 = *(const uint4*)(nebf + (size_t)d3 * (DIM / 2) + 4 * l);
        const float w0 = edge_w(sar, s_b[d0]);
        const float w1 = edge_w(sar, s_b[d1]);
        const float w2 = edge_w(sar, s_b[d2]);
        const float w3 = edge_w(sar, s_b[d3]);
        ACC8(u0, w0) ACC8(u1, w1) ACC8(u2, w2) ACC8(u3, w3)
        wsum += (w0 + w1) + (w2 + w3);
    }
    for (; i + 4 < cb; i += 8) {
        const int d0 = bucket[i];
        const int d1 = bucket[i + 4];
        const uint4 u0 = *(const uint4*)(nebf + (size_t)d0 * (DIM / 2) + 4 * l);
        const uint4 u1 = *(const uint4*)(nebf + (size_t)d1 * (DIM / 2) + 4 * l);
        const float w0 = edge_w(sar, s_b[d0]);
        const float w1 = edge_w(sar, s_b[d1]);
        ACC8(u0, w0) ACC8(u1, w1)
        wsum += w0 + w1;
    }
    for (; i < cb; i += 4) {
        const int d = bucket[i];
        const uint4 u = *(const uint4*)(nebf + (size_t)d * (DIM / 2) + 4 * l);
        const float wv = edge_w(sar, s_b[d]);
        ACC8(u, wv)
        wsum += wv;
    }
    int novf = flags[1];
    novf = (novf > OVF_CAP) ? OVF_CAP : novf;
    for (int j = q; j < novf; j += 4) {
        const int2 pe = ovf[j];
        if (pe.x == row) {
            const uint4 u = *(const uint4*)(nebf + (size_t)pe.y * (DIM / 2) + 4 * l);
            const float wv = edge_w(sar, s_b[pe.y]);
            ACC8(u, wv)
            wsum += wv;
        }
    }
    ROWAGG_REDUCE_STORE
}

extern "C" void kernel_launch(void* const* d_in, const int* in_sizes, int n_in,
                              void* d_out, int out_size, void* d_ws, size_t ws_size,
                              hipStream_t stream) {
    const float* fa    = (const float*)d_in[0];
    const float* fb    = (const float*)d_in[1];
    const void*  edges = d_in[2];
    const float* W     = (const float*)d_in[3];
    const float* bias  = (const float*)d_in[4];
    const float* avec  = (const float*)d_in[5];
    float* out = (float*)d_out;
    char* ws = (char*)d_ws;
    short* nebf  = (short*)(ws + WS_NEBF);
    short* wbf   = (short*)(ws + WS_WBF);
    float* s_a   = (float*)(ws + WS_SA);
    float* s_b   = (float*)(ws + WS_SB);
    int*   cnt   = (int*)(ws + WS_CNT);
    int*   flags = (int*)(ws + WS_FLAG);
    int2*  ovf   = (int2*)(ws + WS_OVF);

    // ws_size is launch-invariant -> same kernel sequence every capture/replay
    const bool wide = (ws_size >= WS_TOTAL_A);

    // 4 graph nodes (was 6): prep(+zero) -> newemb+sa -> scatter -> rowagg
    k_prep<<<1 + PREP_W_BLOCKS + PREP_Z_BLOCKS, 256, 0, stream>>>(
        (const int*)edges, flags, W, wbf, cnt);
    k_newemb_sa<<<NEWEMB_BLOCKS + SA_BLOCKS, 256, 0, stream>>>(
        fb, wbf, bias, avec, nebf, s_b, fa, s_a);
    if (wide) {
        int2* bucket2 = (int2*)(ws + WS_PAIRS);
        k_scatter_w<<<(NEDGE + 255) / 256, 256, 0, stream>>>(
            edges, flags, s_a, s_b, cnt, bucket2, ovf, &flags[1]);
        k_rowagg_w<<<(NA + 3) / 4, 256, 0, stream>>>(
            cnt, bucket2, s_a, s_b, (const unsigned*)nebf, ovf, flags, out);
    } else {
        int* bucket = (int*)(ws + WS_PAIRS);
        k_scatter<<<(NEDGE + 255) / 256, 256, 0, stream>>>(
            edges, flags, cnt, bucket, ovf, &flags[1]);
        k_rowagg<<<(NA + 3) / 4, 256, 0, stream>>>(
            cnt, bucket, s_a, s_b, (const unsigned*)nebf, ovf, flags, out);
    }
}

// Round 10
// 359.495 us; speedup vs baseline: 1.0509x; 1.0509x over previous
//
#include <hip/hip_runtime.h>
#include <math.h>

#define NA 100000
#define NB 100000
#define DIM 128
#define NEDGE 1600000
#define ALPHA 0.1f
#define BCAP 32        // P(Poisson(16) > 32) ~ 1.5e-4 -> ~25 overflow edges, handled exactly
#define OVF_CAP 65536

// ---- workspace layout (bytes, all 64-aligned) ----
// Path A (wide): int2 bucket, total 52,957,120 (proven OK in R8).
// Path B (fallback): int bucket, total 40,157,120 (proven OK in R5).
#define WS_NEBF   0          // 25,600,000  bf16 new_emb[NB*DIM]
#define WS_WBF    25600000   //     32,768  bf16 W[DIM*DIM]
#define WS_SA     25632768   //    400,000  float s_a[NA]
#define WS_SB     26032768   //    400,000  float s_b[NB]
#define WS_CNT    26432768   //    400,000  int cnt[NA] (cursor; counts ALL edges of row)
#define WS_FLAG   26832768   //         64  int flags[16]: [0]=int64-layout, [1]=overflow counter
#define WS_OVF    26832832   //    524,288  int2 ovf[OVF_CAP] = (src,dst)
#define WS_PAIRS  27357120   // bucket array
#define WS_TOTAL_A (27357120 + (size_t)NA * BCAP * 8)   // 52,957,120 (R8 proven)
#define WS_TOTAL_B (27357120 + (size_t)NA * BCAP * 4)   // 40,157,120 (R5 proven)

using bf16x8 = __attribute__((ext_vector_type(8))) short;
using f32x16 = __attribute__((ext_vector_type(16))) float;
using i32x2  = __attribute__((ext_vector_type(2))) int;
using i32x4  = __attribute__((ext_vector_type(4))) int;
using f32x2v = __attribute__((ext_vector_type(2))) float;
using f32x4v = __attribute__((ext_vector_type(4))) float;

__device__ inline short f2bf(float f) {   // RNE float->bf16
    union { float f; unsigned u; } v; v.f = f;
    const unsigned r = (v.u + 0x7FFFu + ((v.u >> 16) & 1u)) >> 16;
    return (short)r;
}

// block 0: edge-layout detect (int64 high words all zero?); blocks 1..64: W -> bf16
__global__ void k_prep(const int* __restrict__ edges32, int* __restrict__ flags,
                       const float* __restrict__ W, short* __restrict__ wbf) {
    if (blockIdx.x == 0) {
        __shared__ int any;
        if (threadIdx.x == 0) any = 0;
        __syncthreads();
        if (edges32[2 * threadIdx.x + 1] != 0) atomicOr(&any, 1);
        __syncthreads();
        if (threadIdx.x == 0) flags[0] = (any == 0) ? 1 : 0;
    } else {
        const int i = (blockIdx.x - 1) * 256 + threadIdx.x;
        if (i < DIM * DIM) wbf[i] = f2bf(W[i]);
    }
}

// new_emb(bf16) = fb @ W^T + b ; s_b = new_emb @ a_bot.  MFMA 32x32x16 bf16.
// fb is a read-once stream -> NT loads (keep L2 for hot data).
__global__ __launch_bounds__(256) void k_newemb(
    const float* __restrict__ fb, const short* __restrict__ wbf,
    const float* __restrict__ bias, const float* __restrict__ avec,
    short* __restrict__ nebf, float* __restrict__ s_b)
{
    const int wv = threadIdx.x >> 6;
    const int lane = threadIdx.x & 63;
    const int tile = blockIdx.x * 4 + wv;
    const int row0 = tile * 32;
    if (row0 >= NB) return;
    const int l31 = lane & 31;
    const int h = lane >> 5;

    f32x16 acc[4];
    #pragma unroll
    for (int nt = 0; nt < 4; ++nt)
        #pragma unroll
        for (int r = 0; r < 16; ++r) acc[nt][r] = 0.f;

    const float* arow = fb + (size_t)(row0 + l31) * DIM;   // A: m = lane&31

    #pragma unroll 2
    for (int s = 0; s < 8; ++s) {
        const int k0 = s * 16 + h * 8;                     // A/B: k = 8*(lane>>5)+j
        const f32x4v a0 = __builtin_nontemporal_load((const f32x4v*)(arow + k0));
        const f32x4v a1 = __builtin_nontemporal_load((const f32x4v*)(arow + k0 + 4));
        bf16x8 af;
        af[0] = f2bf(a0.x); af[1] = f2bf(a0.y); af[2] = f2bf(a0.z); af[3] = f2bf(a0.w);
        af[4] = f2bf(a1.x); af[5] = f2bf(a1.y); af[6] = f2bf(a1.z); af[7] = f2bf(a1.w);
        #pragma unroll
        for (int nt = 0; nt < 4; ++nt) {
            const int n = nt * 32 + l31;                   // B[k][n] = W[n][k]
            const bf16x8 bf = *(const bf16x8*)(wbf + n * DIM + k0);
            acc[nt] = __builtin_amdgcn_mfma_f32_32x32x16_bf16(af, bf, acc[nt], 0, 0, 0);
        }
    }

    float ab[4], bs[4];
    #pragma unroll
    for (int nt = 0; nt < 4; ++nt) {
        ab[nt] = avec[DIM + nt * 32 + l31];   // a_bot
        bs[nt] = bias[nt * 32 + l31];
    }
    float sb[16];
    #pragma unroll
    for (int r = 0; r < 16; ++r) {
        const int row = row0 + (r & 3) + 8 * (r >> 2) + 4 * h;  // C/D row map
        float p = 0.f;
        #pragma unroll
        for (int nt = 0; nt < 4; ++nt) {
            const float v = acc[nt][r] + bs[nt];
            nebf[(size_t)row * DIM + nt * 32 + l31] = f2bf(v);
            p += v * ab[nt];
        }
        #pragma unroll
        for (int m = 16; m; m >>= 1) p += __shfl_xor(p, m, 64);  // reduce over lane&31
        sb[r] = p;
    }
    if (l31 == 0) {
        #pragma unroll
        for (int r = 0; r < 16; ++r)
            s_b[row0 + (r & 3) + 8 * (r >> 2) + 4 * h] = sb[r];
    }
}

// s_a = feature_a @ a_top : one wave per row.  fa is read-once -> NT loads.
__global__ __launch_bounds__(256) void k_sa(
    const float* __restrict__ fa, const float* __restrict__ avec,
    float* __restrict__ s_a)
{
    const int row = blockIdx.x * 4 + (threadIdx.x >> 6);
    if (row >= NA) return;
    const int lane = threadIdx.x & 63;
    const f32x2v v = __builtin_nontemporal_load((const f32x2v*)(fa + (size_t)row * DIM + 2 * lane));
    const float2 a = *(const float2*)(avec + 2 * lane);
    float p = v.x * a.x + v.y * a.y;
    #pragma unroll
    for (int m = 32; m; m >>= 1) p += __shfl_xor(p, m, 64);
    if (lane == 0) s_a[row] = p;
}

__device__ inline float edge_w(float sar, float sb) {
    const float sc = sar + sb;
    const float el = (sc > 0.f) ? sc : ALPHA * expm1f(sc);
    return expf(el);
}

// ---- PATH A: scatter with w computed here, 8B (dst,w) entries.
// Edge stream NT-loaded so it doesn't evict partially-filled bucket lines from L2:
// R8/R9 WRITE_SIZE = 102 MB = 1.6M x 64B = every 8B store evicted dirty with ~1
// entry filled. Bucket (25.6MB) + edge stream (25.6MB) > 32MB L2 -> thrash.
__global__ __launch_bounds__(256) void k_scatter_w(
    const void* __restrict__ edges, const int* __restrict__ flags,
    const float* __restrict__ s_a, const float* __restrict__ s_b,
    int* __restrict__ cnt, int2* __restrict__ bucket,
    int2* __restrict__ ovf, int* __restrict__ ovfcnt)
{
    const int e = blockIdx.x * 256 + threadIdx.x;
    if (e >= NEDGE) return;
    int src, dst;
    if (flags[0]) {
        const i32x4 v = __builtin_nontemporal_load((const i32x4*)edges + e);
        src = v.x; dst = v.z;
    } else {
        const i32x2 v = __builtin_nontemporal_load((const i32x2*)edges + e);
        src = v.x; dst = v.y;
    }
    const float w = edge_w(s_a[src], s_b[dst]);
    const int pos = atomicAdd(&cnt[src], 1);
    if (pos < BCAP) {
        bucket[(src << 5) + pos] = make_int2(dst, __float_as_int(w));
    } else {
        const int o = atomicAdd(ovfcnt, 1);
        if (o < OVF_CAP) ovf[o] = make_int2(src, dst);
    }
}

// ---- PATH B: 4B dst-only entries (R5 proven fallback, untouched) ----
__global__ __launch_bounds__(256) void k_scatter(
    const void* __restrict__ edges, const int* __restrict__ flags,
    int* __restrict__ cnt, int* __restrict__ bucket,
    int2* __restrict__ ovf, int* __restrict__ ovfcnt)
{
    const int e = blockIdx.x * 256 + threadIdx.x;
    if (e >= NEDGE) return;
    int src, dst;
    if (flags[0]) {
        const int4 v = ((const int4*)edges)[e];
        src = v.x; dst = v.z;
    } else {
        const int2 v = ((const int2*)edges)[e];
        src = v.x; dst = v.y;
    }
    const int pos = atomicAdd(&cnt[src], 1);
    if (pos < BCAP) {
        bucket[(src << 5) + pos] = dst;
    } else {
        const int o = atomicAdd(ovfcnt, 1);
        if (o < OVF_CAP) ovf[o] = make_int2(src, dst);
    }
}

// one wave per src row, quarter-wave per edge: 16 lanes x uint4 = full 256B bf16 row,
// 4-deep MLP. Bucket stream NT-loaded, out NT-stored -> nebf gather table stays hot.
#define ACC8(u, wt)                                                             \
    a0 += (wt) * __uint_as_float((u).x << 16);                                  \
    a1 += (wt) * __uint_as_float((u).x & 0xFFFF0000u);                          \
    a2 += (wt) * __uint_as_float((u).y << 16);                                  \
    a3 += (wt) * __uint_as_float((u).y & 0xFFFF0000u);                          \
    a4 += (wt) * __uint_as_float((u).z << 16);                                  \
    a5 += (wt) * __uint_as_float((u).z & 0xFFFF0000u);                          \
    a6 += (wt) * __uint_as_float((u).w << 16);                                  \
    a7 += (wt) * __uint_as_float((u).w & 0xFFFF0000u);

#define ROWAGG_REDUCE                                                           \
    a0 += __shfl_xor(a0, 16, 64); a0 += __shfl_xor(a0, 32, 64);                 \
    a1 += __shfl_xor(a1, 16, 64); a1 += __shfl_xor(a1, 32, 64);                 \
    a2 += __shfl_xor(a2, 16, 64); a2 += __shfl_xor(a2, 32, 64);                 \
    a3 += __shfl_xor(a3, 16, 64); a3 += __shfl_xor(a3, 32, 64);                 \
    a4 += __shfl_xor(a4, 16, 64); a4 += __shfl_xor(a4, 32, 64);                 \
    a5 += __shfl_xor(a5, 16, 64); a5 += __shfl_xor(a5, 32, 64);                 \
    a6 += __shfl_xor(a6, 16, 64); a6 += __shfl_xor(a6, 32, 64);                 \
    a7 += __shfl_xor(a7, 16, 64); a7 += __shfl_xor(a7, 32, 64);                 \
    wsum += __shfl_xor(wsum, 16, 64); wsum += __shfl_xor(wsum, 32, 64);

// PATH A rowagg: w read from bucket (no s_b gather / expf per edge)
__global__ __launch_bounds__(256) void k_rowagg_w(
    const int* __restrict__ cnt, const int2* __restrict__ bucket_all,
    const float* __restrict__ s_a, const float* __restrict__ s_b,
    const unsigned* __restrict__ nebf, const int2* __restrict__ ovf,
    const int* __restrict__ flags, float* __restrict__ out)
{
    const int row = blockIdx.x * 4 + (threadIdx.x >> 6);
    if (row >= NA) return;
    const int lane = threadIdx.x & 63;
    const int l = lane & 15;
    const int q = lane >> 4;
    const int c = cnt[row];
    const int cb = (c > BCAP) ? BCAP : c;
    const i32x2* bkt = (const i32x2*)bucket_all + (row << 5);

    float a0 = 0.f, a1 = 0.f, a2 = 0.f, a3 = 0.f;
    float a4 = 0.f, a5 = 0.f, a6 = 0.f, a7 = 0.f, wsum = 0.f;
    int i = q;
    for (; i + 12 < cb; i += 16) {
        const i32x2 p0 = __builtin_nontemporal_load(bkt + i);
        const i32x2 p1 = __builtin_nontemporal_load(bkt + i + 4);
        const i32x2 p2 = __builtin_nontemporal_load(bkt + i + 8);
        const i32x2 p3 = __builtin_nontemporal_load(bkt + i + 12);
        const uint4 u0 = *(const uint4*)(nebf + (size_t)p0.x * (DIM / 2) + 4 * l);
        const uint4 u1 = *(const uint4*)(nebf + (size_t)p1.x * (DIM / 2) + 4 * l);
        const uint4 u2 = *(const uint4*)(nebf + (size_t)p2.x * (DIM / 2) + 4 * l);
        const uint4 u3 = *(const uint4*)(nebf + (size_t)p3.x * (DIM / 2) + 4 * l);
        const float w0 = __int_as_float(p0.y);
        const float w1 = __int_as_float(p1.y);
        const float w2 = __int_as_float(p2.y);
        const float w3 = __int_as_float(p3.y);
        ACC8(u0, w0) ACC8(u1, w1) ACC8(u2, w2) ACC8(u3, w3)
        wsum += (w0 + w1) + (w2 + w3);
    }
    for (; i + 4 < cb; i += 8) {
        const i32x2 p0 = __builtin_nontemporal_load(bkt + i);
        const i32x2 p1 = __builtin_nontemporal_load(bkt + i + 4);
        const uint4 u0 = *(const uint4*)(nebf + (size_t)p0.x * (DIM / 2) + 4 * l);
        const uint4 u1 = *(const uint4*)(nebf + (size_t)p1.x * (DIM / 2) + 4 * l);
        const float w0 = __int_as_float(p0.y);
        const float w1 = __int_as_float(p1.y);
        ACC8(u0, w0) ACC8(u1, w1)
        wsum += w0 + w1;
    }
    for (; i < cb; i += 4) {
        const i32x2 p = __builtin_nontemporal_load(bkt + i);
        const uint4 u = *(const uint4*)(nebf + (size_t)p.x * (DIM / 2) + 4 * l);
        const float wv = __int_as_float(p.y);
        ACC8(u, wv)
        wsum += wv;
    }
    // exact overflow fold-in (~25 entries; w recomputed, negligible)
    int novf = flags[1];
    novf = (novf > OVF_CAP) ? OVF_CAP : novf;
    const float sar = s_a[row];
    for (int j = q; j < novf; j += 4) {
        const int2 pe = ovf[j];
        if (pe.x == row) {
            const uint4 u = *(const uint4*)(nebf + (size_t)pe.y * (DIM / 2) + 4 * l);
            const float wv = edge_w(sar, s_b[pe.y]);
            ACC8(u, wv)
            wsum += wv;
        }
    }
    ROWAGG_REDUCE
    if (q == 0) {
        const float inv = 1.f / ((wsum == 0.f) ? 1.f : wsum);
        float* o = out + (size_t)row * DIM + 8 * l;
        f32x4v o0, o1;
        o0.x = a0 * inv; o0.y = a1 * inv; o0.z = a2 * inv; o0.w = a3 * inv;
        o1.x = a4 * inv; o1.y = a5 * inv; o1.z = a6 * inv; o1.w = a7 * inv;
        __builtin_nontemporal_store(o0, (f32x4v*)o);
        __builtin_nontemporal_store(o1, (f32x4v*)(o + 4));
    }
}

// PATH B rowagg: w recomputed from s_a + s_b (R5 proven fallback, untouched)
__global__ __launch_bounds__(256) void k_rowagg(
    const int* __restrict__ cnt, const int* __restrict__ bucket_all,
    const float* __restrict__ s_a, const float* __restrict__ s_b,
    const unsigned* __restrict__ nebf, const int2* __restrict__ ovf,
    const int* __restrict__ flags, float* __restrict__ out)
{
    const int row = blockIdx.x * 4 + (threadIdx.x >> 6);
    if (row >= NA) return;
    const int lane = threadIdx.x & 63;
    const int l = lane & 15;
    const int q = lane >> 4;
    const int c = cnt[row];
    const int cb = (c > BCAP) ? BCAP : c;
    const int* bucket = bucket_all + (row << 5);
    const float sar = s_a[row];

    float a0 = 0.f, a1 = 0.f, a2 = 0.f, a3 = 0.f;
    float a4 = 0.f, a5 = 0.f, a6 = 0.f, a7 = 0.f, wsum = 0.f;
    int i = q;
    for (; i + 12 < cb; i += 16) {
        const int d0 = bucket[i];
        const int d1 = bucket[i + 4];
        const int d2 = bucket[i + 8];
        const int d3 = bucket[i + 12];
        const uint4 u0 = *(const uint4*)(nebf + (size_t)d0 * (DIM / 2) + 4 * l);
        const uint4 u1 = *(const uint4*)(nebf + (size_t)d1 * (DIM / 2) + 4 * l);
        const uint4 u2 = *(const uint4*)(nebf + (size_t)d2 * (DIM / 2) + 4 * l);
        const uint4 u3 = *(const uint4*)(nebf + (size_t)d3 * (DIM / 2) + 4 * l);
        const float w0 = edge_w(sar, s_b[d0]);
        const float w1 = edge_w(sar, s_b[d1]);
        const float w2 = edge_w(sar, s_b[d2]);
        const float w3 = edge_w(sar, s_b[d3]);
        ACC8(u0, w0) ACC8(u1, w1) ACC8(u2, w2) ACC8(u3, w3)
        wsum += (w0 + w1) + (w2 + w3);
    }
    for (; i + 4 < cb; i += 8) {
        const int d0 = bucket[i];
        const int d1 = bucket[i + 4];
        const uint4 u0 = *(const uint4*)(nebf + (size_t)d0 * (DIM / 2) + 4 * l);
        const uint4 u1 = *(const uint4*)(nebf + (size_t)d1 * (DIM / 2) + 4 * l);
        const float w0 = edge_w(sar, s_b[d0]);
        const float w1 = edge_w(sar, s_b[d1]);
        ACC8(u0, w0) ACC8(u1, w1)
        wsum += w0 + w1;
    }
    for (; i < cb; i += 4) {
        const int d = bucket[i];
        const uint4 u = *(const uint4*)(nebf + (size_t)d * (DIM / 2) + 4 * l);
        const float wv = edge_w(sar, s_b[d]);
        ACC8(u, wv)
        wsum += wv;
    }
    int novf = flags[1];
    novf = (novf > OVF_CAP) ? OVF_CAP : novf;
    for (int j = q; j < novf; j += 4) {
        const int2 pe = ovf[j];
        if (pe.x == row) {
            const uint4 u = *(const uint4*)(nebf + (size_t)pe.y * (DIM / 2) + 4 * l);
            const float wv = edge_w(sar, s_b[pe.y]);
            ACC8(u, wv)
            wsum += wv;
        }
    }
    ROWAGG_REDUCE
    if (q == 0) {
        const float inv = 1.f / ((wsum == 0.f) ? 1.f : wsum);
        float* o = out + (size_t)row * DIM + 8 * l;
        *(float4*)o       = make_float4(a0 * inv, a1 * inv, a2 * inv, a3 * inv);
        *(float4*)(o + 4) = make_float4(a4 * inv, a5 * inv, a6 * inv, a7 * inv);
    }
}

extern "C" void kernel_launch(void* const* d_in, const int* in_sizes, int n_in,
                              void* d_out, int out_size, void* d_ws, size_t ws_size,
                              hipStream_t stream) {
    const float* fa    = (const float*)d_in[0];
    const float* fb    = (const float*)d_in[1];
    const void*  edges = d_in[2];
    const float* W     = (const float*)d_in[3];
    const float* bias  = (const float*)d_in[4];
    const float* avec  = (const float*)d_in[5];
    float* out = (float*)d_out;
    char* ws = (char*)d_ws;
    short* nebf  = (short*)(ws + WS_NEBF);
    short* wbf   = (short*)(ws + WS_WBF);
    float* s_a   = (float*)(ws + WS_SA);
    float* s_b   = (float*)(ws + WS_SB);
    int*   cnt   = (int*)(ws + WS_CNT);
    int*   flags = (int*)(ws + WS_FLAG);
    int2*  ovf   = (int2*)(ws + WS_OVF);

    // ws_size is launch-invariant -> same kernel sequence every capture/replay
    const bool wide = (ws_size >= WS_TOTAL_A);

    // R8-proven 6-node structure (R9's node-merge regressed; reverted)
    (void)hipMemsetAsync(ws + WS_CNT, 0, (size_t)NA * sizeof(int) + 64, stream);
    k_prep<<<1 + (DIM * DIM + 255) / 256, 256, 0, stream>>>((const int*)edges, flags, W, wbf);
    k_newemb<<<(NB / 32 + 3) / 4, 256, 0, stream>>>(fb, wbf, bias, avec, nebf, s_b);
    k_sa<<<(NA + 3) / 4, 256, 0, stream>>>(fa, avec, s_a);
    if (wide) {
        int2* bucket2 = (int2*)(ws + WS_PAIRS);
        k_scatter_w<<<(NEDGE + 255) / 256, 256, 0, stream>>>(
            edges, flags, s_a, s_b, cnt, bucket2, ovf, &flags[1]);
        k_rowagg_w<<<(NA + 3) / 4, 256, 0, stream>>>(
            cnt, bucket2, s_a, s_b, (const unsigned*)nebf, ovf, flags, out);
    } else {
        int* bucket = (int*)(ws + WS_PAIRS);
        k_scatter<<<(NEDGE + 255) / 256, 256, 0, stream>>>(
            edges, flags, cnt, bucket, ovf, &flags[1]);
        k_rowagg<<<(NA + 3) / 4, 256, 0, stream>>>(
            cnt, bucket, s_a, s_b, (const unsigned*)nebf, ovf, flags, out);
    }
}